// Round 8
// baseline (127.193 us; speedup 1.0000x reference)
//
#include <hip/hip_runtime.h>

// Composite-filter formulation:
//   out[o] = sum_{k=0..54} Cp[r][k] * x[n0 - k],
//     r = (2o+32) % 3, n0 = (2o+32-r)/3,
//     Cp[p][k] = C[p+3k], C[j] = sum_m b[m]*h[j-2m]
// fused_fast covers 50 <= o < n_out; boundary kernel covers o<50 and o>=n_out.
//
// R7 post-mortem: L1-traffic halving was neutral -> not L1-bound; surviving
// theory is HBM-latency exposure (x > L2, one load-burst per short-lived wave).
// R8: persistent 4-tile blocks with a REGISTER DOUBLE BUFFER: tile t+1's 16
// window loads issue before tile t's 660-FMA stream -> every load gets a
// 1320-cycle shadow, latency hiding no longer depends on occupancy.

#define TPB 256
#define RPT 12                    // outputs per thread
#define OTILE (TPB * RPT)         // 3072 outputs per tile
#define TPBK 4                    // tiles per block
#define NBLOCKS 1024              // NBLOCKS*TPBK = 4096 tiles = n_out/OTILE
#define XTILE2 2112               // edge-path staging (needs 2104)
#define NTAPS 55
#define CPSTRIDE 56               // phase-major coeff stride (zero-padded, float4-aligned)

__global__ void build_coeffs(const float* __restrict__ h,
                             const float* __restrict__ b,
                             float* __restrict__ cp) {
    __shared__ float h_s[63];
    __shared__ float b_s[51];
    const int tid = threadIdx.x;
    if (tid < 63) h_s[tid] = h[tid];
    if (tid < 51) b_s[tid] = b[tid];
    __syncthreads();
    for (int idx = tid; idx < 3 * CPSTRIDE; idx += blockDim.x) {
        const int p = idx / CPSTRIDE;
        const int k = idx - p * CPSTRIDE;
        float acc = 0.0f;
        if (k < NTAPS) {
            const int j = p + 3 * k;
            for (int m = 0; m <= 50; ++m) {
                const int hi = j - 2 * m;
                if (hi >= 0 && hi <= 62) acc += b_s[m] * h_s[hi];
            }
        }
        cp[idx] = acc;
    }
}

// Block 0 = head (o in [0,50)), block 1 = tail (o in [n_out, out_size)).
__global__ __launch_bounds__(128) void boundary_fix(
    const float* __restrict__ x, const float* __restrict__ h,
    const float* __restrict__ b, float* __restrict__ out,
    int n_in, int n_out, int out_size)
{
    __shared__ float h_s[63];
    __shared__ float b_s[51];
    __shared__ float x_s[64];
    __shared__ float u_s[50];

    const int tid = threadIdx.x;
    if (tid < 63) h_s[tid] = h[tid];
    if (tid < 51) b_s[tid] = b[tid];

    if (blockIdx.x == 0) {
        if (tid < 44) x_s[tid] = (tid < n_in) ? x[tid] : 0.0f;
        __syncthreads();
        if (tid < 50) {
            const int s  = 2 * tid + 32;
            const int p0 = s % 3;
            const int q  = s / 3;
            float u = 0.0f;
            #pragma unroll
            for (int i = 0; i <= 20; ++i) {
                const int xi = q - i;
                u += h_s[p0 + 3 * i] * ((xi >= 0) ? x_s[xi] : 0.0f);
            }
            u_s[tid] = u;
        }
        __syncthreads();
        if (tid < 50) {
            float acc = 0.0f;
            for (int t = 0; t <= tid; ++t) acc += b_s[tid - t] * u_s[t];
            out[tid] = acc;
        }
    } else {
        const int t0   = n_out - 50;
        const int qmin = (2 * t0 + 32) / 3;
        const int xb   = qmin - 20;
        if (tid < 64) {
            const int xi = xb + tid;
            x_s[tid] = (xi >= 0 && xi < n_in) ? x[xi] : 0.0f;
        }
        __syncthreads();
        if (tid < 50) {
            const int t  = t0 + tid;
            const int s  = 2 * t + 32;
            const int p0 = s % 3;
            const int q  = s / 3;
            const int base = q - xb;
            float u = 0.0f;
            #pragma unroll
            for (int i = 0; i <= 20; ++i)
                u += h_s[p0 + 3 * i] * x_s[base - i];
            u_s[tid] = u;
        }
        __syncthreads();
        const int n_tail = out_size - n_out;   // 96
        if (tid < n_tail) {
            float acc = 0.0f;
            for (int j = tid; j <= 49; ++j) acc += b_s[tid + 50 - j] * u_s[j];
            out[n_out + tid] = acc;
        }
    }
}

// Group g covers taps k=4g..4g+3 for 12 outputs d=0..11.
// delta_d = {0,1,2,2,3,4,4,5,6,6,7,8}, phase r_d = (2+2d)%3 -> q2/q1/q0 cycle.
#define GRP12(g, A, B, C, D) {                                          \
    const float4 q2 = c2q[g];                                           \
    const float4 q1 = c1q[g];                                           \
    const float4 q0 = c0q[g];                                           \
    a0  += q2.x * C.z;  a1  += q1.x * C.w;  a2  += q0.x * B.x;          \
    a3  += q2.x * B.x;  a4  += q1.x * B.y;  a5  += q0.x * B.z;          \
    a6  += q2.x * B.z;  a7  += q1.x * B.w;  a8  += q0.x * A.x;          \
    a9  += q2.x * A.x;  a10 += q1.x * A.y;  a11 += q0.x * A.z;          \
    a0  += q2.y * C.y;  a1  += q1.y * C.z;  a2  += q0.y * C.w;          \
    a3  += q2.y * C.w;  a4  += q1.y * B.x;  a5  += q0.y * B.y;          \
    a6  += q2.y * B.y;  a7  += q1.y * B.z;  a8  += q0.y * B.w;          \
    a9  += q2.y * B.w;  a10 += q1.y * A.x;  a11 += q0.y * A.y;          \
    a0  += q2.z * C.x;  a1  += q1.z * C.y;  a2  += q0.z * C.z;          \
    a3  += q2.z * C.z;  a4  += q1.z * C.w;  a5  += q0.z * B.x;          \
    a6  += q2.z * B.x;  a7  += q1.z * B.y;  a8  += q0.z * B.z;          \
    a9  += q2.z * B.z;  a10 += q1.z * B.w;  a11 += q0.z * A.x;          \
    a0  += q2.w * D.w;  a1  += q1.w * C.x;  a2  += q0.w * C.y;          \
    a3  += q2.w * C.y;  a4  += q1.w * C.z;  a5  += q0.w * C.w;          \
    a6  += q2.w * C.w;  a7  += q1.w * B.x;  a8  += q0.w * B.y;          \
    a9  += q2.w * B.y;  a10 += q1.w * B.z;  a11 += q0.w * B.w; }

#define GRP12T(g, A, B, C) {                                            \
    const float4 q2 = c2q[g];                                           \
    const float4 q1 = c1q[g];                                           \
    const float4 q0 = c0q[g];                                           \
    a0  += q2.x * C.z;  a1  += q1.x * C.w;  a2  += q0.x * B.x;          \
    a3  += q2.x * B.x;  a4  += q1.x * B.y;  a5  += q0.x * B.z;          \
    a6  += q2.x * B.z;  a7  += q1.x * B.w;  a8  += q0.x * A.x;          \
    a9  += q2.x * A.x;  a10 += q1.x * A.y;  a11 += q0.x * A.z;          \
    a0  += q2.y * C.y;  a1  += q1.y * C.z;  a2  += q0.y * C.w;          \
    a3  += q2.y * C.w;  a4  += q1.y * B.x;  a5  += q0.y * B.y;          \
    a6  += q2.y * B.y;  a7  += q1.y * B.z;  a8  += q0.y * B.w;          \
    a9  += q2.y * B.w;  a10 += q1.y * A.x;  a11 += q0.y * A.y;          \
    a0  += q2.z * C.x;  a1  += q1.z * C.y;  a2  += q0.z * C.z;          \
    a3  += q2.z * C.z;  a4  += q1.z * C.w;  a5  += q0.z * B.x;          \
    a6  += q2.z * B.x;  a7  += q1.z * B.y;  a8  += q0.z * B.z;          \
    a9  += q2.z * B.z;  a10 += q1.z * B.w;  a11 += q0.z * A.x; }

#define LOAD16(P, S) {                                                  \
    P##15 = S[15]; P##14 = S[14]; P##13 = S[13]; P##12 = S[12];         \
    P##11 = S[11]; P##10 = S[10]; P##9  = S[9];  P##8  = S[8];          \
    P##7  = S[7];  P##6  = S[6];  P##5  = S[5];  P##4  = S[4];          \
    P##3  = S[3];  P##2  = S[2];  P##1  = S[1];  P##0  = S[0]; }

#define CONV12R(P) {                                                    \
    GRP12( 0, P##15, P##14, P##13, P##12);                              \
    GRP12( 1, P##14, P##13, P##12, P##11);                              \
    GRP12( 2, P##13, P##12, P##11, P##10);                              \
    GRP12( 3, P##12, P##11, P##10, P##9);                               \
    GRP12( 4, P##11, P##10, P##9,  P##8);                               \
    GRP12( 5, P##10, P##9,  P##8,  P##7);                               \
    GRP12( 6, P##9,  P##8,  P##7,  P##6);                               \
    GRP12( 7, P##8,  P##7,  P##6,  P##5);                               \
    GRP12( 8, P##7,  P##6,  P##5,  P##4);                               \
    GRP12( 9, P##6,  P##5,  P##4,  P##3);                               \
    GRP12(10, P##5,  P##4,  P##3,  P##2);                               \
    GRP12(11, P##4,  P##3,  P##2,  P##1);                               \
    GRP12(12, P##3,  P##2,  P##1,  P##0);                               \
    GRP12T(13, P##2, P##1, P##0); }

// One pipeline phase: prefetch tile+1 into NXT, repair CUR if edge tile,
// compute+store tile from CUR, advance.
#define PHASE(CUR, NXT) {                                               \
    int tnext = tile + 1; if (tnext > tlast) tnext = tlast;             \
    int nbn = 2048 * tnext - 44;                                        \
    if (nbn < 0) nbn = 0;                                               \
    if (nbn > n_in - XTILE2) nbn = n_in - XTILE2;                       \
    const float4* gn = (const float4*)(x + nbn + 8 * tid);              \
    LOAD16(NXT, gn);                                                    \
    __builtin_amdgcn_sched_barrier(0);                                  \
    const int nt0 = 2048 * tile - 44;                                   \
    if (nt0 < 0 || nt0 + XTILE2 > n_in) {                               \
        for (int i = tid; i < XTILE2; i += TPB) {                       \
            const int n = nt0 + i;                                      \
            x_s[i] = (n >= 0 && n < n_in) ? x[n] : 0.0f;                \
        }                                                               \
        __syncthreads();                                                \
        const float4* xe = (const float4*)(x_s) + 2 * tid;              \
        LOAD16(CUR, xe);                                                \
    }                                                                   \
    float a0=0.f,a1=0.f,a2=0.f,a3=0.f,a4=0.f,a5=0.f;                    \
    float a6=0.f,a7=0.f,a8=0.f,a9=0.f,a10=0.f,a11=0.f;                  \
    CONV12R(CUR);                                                       \
    const int ob = tile * OTILE + 12 * tid;                             \
    if (ob >= 50 && ob + 11 < n_out) {                                  \
        float4* o4 = (float4*)(out + ob);                               \
        o4[0] = make_float4(a0, a1, a2,  a3);                           \
        o4[1] = make_float4(a4, a5, a6,  a7);                           \
        o4[2] = make_float4(a8, a9, a10, a11);                          \
    } else {                                                            \
        const float accs[RPT] = {a0,a1,a2,a3,a4,a5,a6,a7,a8,a9,a10,a11};\
        for (int d = 0; d < RPT; ++d) {                                 \
            const int o = ob + d;                                       \
            if (o >= 50 && o < n_out) out[o] = accs[d];                 \
        }                                                               \
    }                                                                   \
    tile = tnext; }

__global__ __launch_bounds__(TPB) void fused_fast(
    const float* __restrict__ x, const float* __restrict__ cp,
    float* __restrict__ out, int n_in, int n_out)
{
    __shared__ float x_s[XTILE2];

    const int tid   = threadIdx.x;
    int tile        = blockIdx.x * TPBK;
    const int tlast = tile + TPBK - 1;

    const float4* c2q = (const float4*)(cp + 2 * CPSTRIDE);  // phase 2 (o%3==0)
    const float4* c1q = (const float4*)(cp + 1 * CPSTRIDE);
    const float4* c0q = (const float4*)(cp + 0 * CPSTRIDE);

    float4 A0,A1,A2,A3,A4,A5,A6,A7,A8,A9,A10,A11,A12,A13,A14,A15;
    float4 B0,B1,B2,B3,B4,B5,B6,B7,B8,B9,B10,B11,B12,B13,B14,B15;

    // Prologue: load first tile's window (clamped; edge repaired at compute).
    {
        int nb0 = 2048 * tile - 44;
        if (nb0 < 0) nb0 = 0;
        if (nb0 > n_in - XTILE2) nb0 = n_in - XTILE2;
        const float4* g0 = (const float4*)(x + nb0 + 8 * tid);
        LOAD16(A, g0);
    }

    for (int it = 0; it < TPBK / 2; ++it) {
        PHASE(A, B);
        PHASE(B, A);
    }
}

extern "C" void kernel_launch(void* const* d_in, const int* in_sizes, int n_in_arrs,
                              void* d_out, int out_size, void* d_ws, size_t ws_size,
                              hipStream_t stream) {
    const float* x = (const float*)d_in[0];
    const float* h = (const float*)d_in[1];
    const float* b = (const float*)d_in[2];
    float* out = (float*)d_out;
    float* cp  = (float*)d_ws;                        // 3*56*4 = 672 bytes

    const int n_in  = in_sizes[0];                    // 8388608
    const int n_out = (int)((long long)n_in * 3 / 2); // 12582912 = 4096*OTILE

    build_coeffs<<<1, 64, 0, stream>>>(h, b, cp);
    fused_fast<<<NBLOCKS, TPB, 0, stream>>>(x, cp, out, n_in, n_out);
    boundary_fix<<<2, 128, 0, stream>>>(x, h, b, out, n_in, n_out, out_size);
}